// Round 11
// baseline (6488.862 us; speedup 1.0000x reference)
//
#include <hip/hip_runtime.h>

#define TT 512
#define GG 4128
#define GPAD 4224
#define NBLK2 256
#define NTHR2 512

typedef _Float16 f16;
typedef _Float16 half8 __attribute__((ext_vector_type(8)));
typedef _Float16 half4 __attribute__((ext_vector_type(4)));
typedef float f32x4 __attribute__((ext_vector_type(4)));
typedef unsigned u32x4 __attribute__((ext_vector_type(4)));
typedef unsigned long long ull;

__device__ __forceinline__ half8 h8(uint4 v) {
  union { uint4 u; half8 h; } c; c.u = v; return c.h;
}
__device__ __forceinline__ half8 h8v(u32x4 v) {
  union { u32x4 u; half8 h; } c; c.u = v; return c.h;
}

// coherent (L1/L2-bypassing to the coherence point) 16B load
__device__ __forceinline__ u32x4 ld_cohx4(const unsigned* p) {
  u32x4 r;
  asm volatile("global_load_dwordx4 %0, %1, off sc0 sc1"
               : "=v"(r) : "v"(p) : "memory");
  return r;
}

// ---------------- transpose + f32->f16 convert: in[R][C] f32 -> out[C][R] f16 ----
__global__ void k_transpose_cvt(const float* __restrict__ in, f16* __restrict__ out,
                                int R, int C) {
  __shared__ float tile[32][33];
  int bx = blockIdx.x * 32, by = blockIdx.y * 32;
  int tx = threadIdx.x & 31, ty = threadIdx.x >> 5;
#pragma unroll
  for (int j = 0; j < 4; ++j) {
    int r = by + ty + j * 8;
    tile[ty + j * 8][tx] = in[(long)r * C + bx + tx];
  }
  __syncthreads();
#pragma unroll
  for (int j = 0; j < 4; ++j) {
    int c = bx + ty + j * 8;
    out[(long)c * R + by + tx] = (f16)tile[tx][ty + j * 8];
  }
}

// ---------------- phase 1: Z = X@W + bias, scattered into Zm / Zg layouts -------
// Zm: [t][b][32] f16
// Zg: [t][x 8][j 32][b' 4][u' 32][q 4] f16  (x=b>>2, b'=b&3, gate col n =
//      32 + q*1024 + j*32 + u')
__global__ __launch_bounds__(256) void k_gemm_xw(
    const float* __restrict__ X,
    const f16* __restrict__ Bt,
    const float* __restrict__ bias,
    f16* __restrict__ Zm,
    f16* __restrict__ Zg) {
  __shared__ f16 As[128 * 32];
  __shared__ f16 Bs[128 * 32];
  const int m0 = blockIdx.x * 128;
  const int n0 = blockIdx.y * 128;
  const int tid = threadIdx.x;
  const int wave = tid >> 6, lane = tid & 63;
  const int mrow = (wave & 1) * 64, ncol = (wave >> 1) * 64;
  f32x4 acc[4][4];
#pragma unroll
  for (int i = 0; i < 4; ++i)
#pragma unroll
    for (int j = 0; j < 4; ++j)
      acc[i][j] = (f32x4){0.f, 0.f, 0.f, 0.f};

  float4 ra[4];
  uint4 rb[2];
  auto load_tiles = [&](int k0) {
#pragma unroll
    for (int q = 0; q < 4; ++q) {
      int flat = q * 256 + tid;
      int r = flat >> 3, s = flat & 7;
      ra[q] = *(const float4*)(X + (long)(m0 + r) * 1024 + k0 + s * 4);
    }
#pragma unroll
    for (int q = 0; q < 2; ++q) {
      int flat = q * 256 + tid;
      int r = flat >> 2, s = flat & 3;
      rb[q] = *(const uint4*)(Bt + (long)(n0 + r) * 1024 + k0 + s * 8);
    }
  };
  load_tiles(0);
  for (int kt = 0; kt < 32; ++kt) {
    __syncthreads();
#pragma unroll
    for (int q = 0; q < 4; ++q) {
      int flat = q * 256 + tid;
      half4 h;
      h[0] = (f16)ra[q].x; h[1] = (f16)ra[q].y;
      h[2] = (f16)ra[q].z; h[3] = (f16)ra[q].w;
      *(half4*)((char*)As + flat * 8) = h;
    }
#pragma unroll
    for (int q = 0; q < 2; ++q) {
      int flat = q * 256 + tid;
      *(uint4*)((char*)Bs + flat * 16) = rb[q];
    }
    __syncthreads();
    if (kt + 1 < 32) load_tiles((kt + 1) * 32);
    const int kseg2 = ((lane >> 4) * 8) * 2;
    half8 af[4], bf[4];
#pragma unroll
    for (int i = 0; i < 4; ++i) {
      int r = mrow + i * 16 + (lane & 15);
      af[i] = *(const half8*)((const char*)As + r * 64 + kseg2);
      int c = ncol + i * 16 + (lane & 15);
      bf[i] = *(const half8*)((const char*)Bs + c * 64 + kseg2);
    }
#pragma unroll
    for (int i = 0; i < 4; ++i)
#pragma unroll
      for (int j = 0; j < 4; ++j)
        acc[i][j] = __builtin_amdgcn_mfma_f32_16x16x32_f16(af[i], bf[j], acc[i][j], 0, 0, 0);
  }
  // scatter epilogue
#pragma unroll
  for (int j = 0; j < 4; ++j) {
    int n = n0 + ncol + j * 16 + (lane & 15);
    if (n < GG) {
      float bv = bias[n];
      const int isM = (n < 32);
      int q = 0, u4 = 0, jj = 0;
      if (!isM) {
        int k = n - 32;
        q = k >> 10;
        int gu = k & 1023;
        jj = gu >> 5;
        u4 = gu & 31;
      }
#pragma unroll
      for (int i = 0; i < 4; ++i) {
#pragma unroll
        for (int r = 0; r < 4; ++r) {
          int m = m0 + mrow + i * 16 + (lane >> 4) * 4 + r;
          int b = m >> 9, tt2 = m & 511;
          f16 v = (f16)(acc[i][j][r] + bv);
          if (isM)
            Zm[((long)(tt2 * 32 + b)) * 32 + n] = v;
          else
            Zg[(((((long)tt2 * 8 + (b >> 2)) * 32 + jj) * 4 + (b & 3)) * 32 + u4) * 4 + q] = v;
        }
      }
    }
  }
}

// ---------------- phase 2 helpers ----------------
__device__ __forceinline__ float sigm(float x) { return 1.f / (1.f + __expf(-x)); }
__device__ __forceinline__ float tanh_(float x) {
  float ax = fabsf(x);
  float e = __expf(-2.f * ax);
  float t = (1.f - e) / (1.f + e);
  return copysignf(t, x);
}
#define AG_LD(p) __hip_atomic_load((p), __ATOMIC_RELAXED, __HIP_MEMORY_SCOPE_AGENT)
#define AG_ST(p, v) __hip_atomic_store((p), (v), __ATOMIC_RELAXED, __HIP_MEMORY_SCOPE_AGENT)

__device__ __forceinline__ void bar_lds() {
  asm volatile("s_waitcnt lgkmcnt(0)" ::: "memory");
  __builtin_amdgcn_sched_barrier(0);
  __builtin_amdgcn_s_barrier();
  __builtin_amdgcn_sched_barrier(0);
}

// ---------------- phase 2: persistent recurrent kernel ----------------
// 256 blocks x 512 threads. 8 INDEPENDENT groups: group x = blocks with
// blockIdx%8==x (round-robin -> all on XCD x), handling batches 4x..4x+3
// for all 512 steps with ZERO inter-group communication. Within a group,
// block j owns units [j*32,+32) + redundant 32 master cols, ksplit-8.
// h exchange: 8KB/group/step through (ideally XCD-local) L2; f16-pair words.
// SYNC: only waves 0,1 publish h (combine threads tid<128); each drains its
// own vmcnt and sets wflag[x*64 + j*2 + wave] = t+1 (monotonic). Consumers
// poll their group's 64 flags lane-parallel (>=). No end-of-step barrier.
// Overwrite safety: flag>=t implies that block passed bar2 of step t-1,
// which is after ALL its 8 waves A-loaded h(t-1) -> publishing h(t+1) over
// h(t-1) parity is safe. Liveness: monotonic flags, all 256 blocks resident.
// LDS (21KB): zp[kq8][gt8][lr16][b'4] f32 @0 | zpm[kq8][mt2][lr16][b'4]
//             @16K | zr[col32][b'4] @20K.
__global__ __launch_bounds__(NTHR2, 1) void k_onlstm(
    const f16* __restrict__ Zm, const f16* __restrict__ Zg,
    const f16* __restrict__ Rt, unsigned* __restrict__ hbuf,
    unsigned* __restrict__ wflag, float* __restrict__ Y) {
  extern __shared__ char lds[];
  const int x = blockIdx.x & 7, j = blockIdx.x >> 3;
  const int tid = threadIdx.x;
  const int wave = tid >> 6, lane = tid & 63;
  const int lr = lane & 15, lq = lane >> 4;
  const int kq = wave;                  // k-slice 0..7 (K=128)
  const int L0 = j >> 1;                // level of this block's 32 units
  const int bp = tid >> 5, up = tid & 31;   // combine role (tid<128)
  const int mcol = tid & 31, mbp = tid >> 5;  // masters-reduce role (tid<128)

  // pinned B fragments: gates 32 uint4 (8 coltiles x 4 ks), masters 8 uint4
  uint4 bq[32], bm[8];
  {
#pragma unroll
    for (int gt = 0; gt < 8; ++gt) {
      int q = gt >> 1, half = gt & 1;
      int col = 32 + q * 1024 + j * 32 + half * 16 + lr;
#pragma unroll
      for (int ks = 0; ks < 4; ++ks)
        bq[gt * 4 + ks] = *(const uint4*)(Rt + (long)col * 1024 + kq * 128 + ks * 32 + lq * 8);
    }
#pragma unroll
    for (int mt = 0; mt < 2; ++mt) {
      int col = mt * 16 + lr;
#pragma unroll
      for (int ks = 0; ks < 4; ++ks)
        bm[mt * 4 + ks] = *(const uint4*)(Rt + (long)col * 1024 + kq * 128 + ks * 32 + lq * 8);
    }
#pragma unroll
    for (int i = 0; i < 32; ++i)
      asm volatile("" : "+v"(bq[i].x), "+v"(bq[i].y), "+v"(bq[i].z), "+v"(bq[i].w));
#pragma unroll
    for (int i = 0; i < 8; ++i)
      asm volatile("" : "+v"(bm[i].x), "+v"(bm[i].y), "+v"(bm[i].z), "+v"(bm[i].w));
  }
  float creg = 0.f;  // combine threads: c-state of unit j*32+up, batch 4x+bp
  // A-frag word base: batch row lr&3 (rows 4..15 replicated, outputs unused)
  const int wbase = (x * 4 + (lr & 3)) * 512 + kq * 64 + lq * 4;

  for (int t = 0; t < TT; ++t) {
    // --- prefetch immutable inputs ---
    half4 zxh;
    float zmv = 0.f;
    if (tid < 128) {
      zxh = *(const half4*)(Zg + (((((long)t * 8 + x) * 32 + j) * 4 + bp) * 32 + up) * 4);
      zmv = (float)Zm[((long)t * 32 + x * 4 + mbp) * 32 + mcol];
    }
    // --- poll this group's 64 wave-flags (monotonic >=) ---
    if (t > 0) {
      const unsigned tg = (unsigned)t;
      const unsigned* wf = wflag + x * 64;
      for (;;) {
        unsigned v = AG_LD(wf + lane);
        if (__all((int)(v >= tg))) break;
      }
    }
    __builtin_amdgcn_sched_barrier(0);
    // --- load own A-fragments (4 batches x K=128 slice) ---
    const unsigned* hb = hbuf + (t & 1) * 16384;
    u32x4 ha[4];
#pragma unroll
    for (int ks = 0; ks < 4; ++ks)
      ha[ks] = ld_cohx4(hb + wbase + ks * 16);
    asm volatile("s_waitcnt vmcnt(0)" ::: "memory");
    __builtin_amdgcn_sched_barrier(0);
    // --- MFMA: 8 gate tiles + 2 master tiles, A rows 0..3 = batches ---
    f32x4 accg[8], accm[2];
#pragma unroll
    for (int gt = 0; gt < 8; ++gt) accg[gt] = (f32x4){0.f, 0.f, 0.f, 0.f};
#pragma unroll
    for (int mt = 0; mt < 2; ++mt) accm[mt] = (f32x4){0.f, 0.f, 0.f, 0.f};
#pragma unroll
    for (int ks = 0; ks < 4; ++ks) {
      half8 a = h8v(ha[ks]);
#pragma unroll
      for (int gt = 0; gt < 8; ++gt)
        accg[gt] = __builtin_amdgcn_mfma_f32_16x16x32_f16(a, h8(bq[gt * 4 + ks]), accg[gt], 0, 0, 0);
#pragma unroll
      for (int mt = 0; mt < 2; ++mt)
        accm[mt] = __builtin_amdgcn_mfma_f32_16x16x32_f16(a, h8(bm[mt * 4 + ks]), accm[mt], 0, 0, 0);
    }
    // --- store partials (only lq==0 holds valid C rows 0..3 = batches) ---
    if (lq == 0) {
#pragma unroll
      for (int gt = 0; gt < 8; ++gt)
        *(f32x4*)(lds + (((kq * 8 + gt) * 16 + lr) << 4)) = accg[gt];
#pragma unroll
      for (int mt = 0; mt < 2; ++mt)
        *(f32x4*)(lds + 16384 + (((kq * 2 + mt) * 16 + lr) << 4)) = accm[mt];
    }
    bar_lds();  // bar1: zp + zpm visible
    // --- reduces (tid<128): gate z (regs) + masters zr (LDS) ---
    float z[4];
    if (tid < 128) {
#pragma unroll
      for (int q = 0; q < 4; ++q) {
        int gt = q * 2 + (up >> 4), lr2 = up & 15;
        float s = 0.f;
#pragma unroll
        for (int k8 = 0; k8 < 8; ++k8)
          s += *(const float*)(lds + (((k8 * 8 + gt) * 16 + lr2) << 4) + ((bp) << 2));
        z[q] = s + (float)zxh[q];
      }
      {
        int mt = mcol >> 4, cl = mcol & 15;
        float s = 0.f;
#pragma unroll
        for (int k8 = 0; k8 < 8; ++k8)
          s += *(const float*)(lds + 16384 + (((k8 * 2 + mt) * 16 + cl) << 4) + (mbp << 2));
        s += zmv;
        *(float*)(lds + 20480 + ((mcol * 4 + mbp) << 2)) = s;
      }
    }
    bar_lds();  // bar2: zr visible
    // --- combine threads: per-thread cumsoftmax + gates + c/h + publish ---
    if (tid < 128) {
      float vf[16], vi[16];
#pragma unroll
      for (int jj = 0; jj < 16; ++jj) {
        vf[jj] = *(const float*)(lds + 20480 + ((jj * 4 + bp) << 2));
        vi[jj] = *(const float*)(lds + 20480 + (((16 + jj) * 4 + bp) << 2));
      }
      float mf = vf[0], mi = vi[0];
#pragma unroll
      for (int jj = 1; jj < 16; ++jj) { mf = fmaxf(mf, vf[jj]); mi = fmaxf(mi, vi[jj]); }
      float sf = 0.f, pf = 0.f, si = 0.f, pi = 0.f;
#pragma unroll
      for (int jj = 0; jj < 16; ++jj) {
        float ef = __expf(vf[jj] - mf);
        sf += ef;
        if (jj <= L0) pf += ef;
        float ei = __expf(vi[jj] - mi);
        si += ei;
        if (jj >= L0) pi += ei;
      }
      float fm = pf / sf, im = pi / si;
      float f = sigm(z[0]), i_ = sigm(z[1]), o = sigm(z[2]);
      float ci = tanh_(z[3]);
      float ov = fm * im;
      float cn = ov * (f * creg + i_ * ci) + (fm - ov) * creg + (im - ov) * ci;
      creg = cn;
      float hval = o * tanh_(cn);
      // publish f16 pair (units up, up+1) for batch 4x+bp
      float hp = __shfl_xor(hval, 1);
      if (!(up & 1)) {
        union { f16 h[2]; unsigned w; } pk;
        pk.h[0] = (f16)hval;
        pk.h[1] = (f16)hp;
        AG_ST(hbuf + ((t + 1) & 1) * 16384 + (x * 4 + bp) * 512 + j * 16 + (up >> 1), pk.w);
      }
      asm volatile("s_waitcnt vmcnt(0)" ::: "memory");
      __builtin_amdgcn_sched_barrier(0);
      if (lane == 0) AG_ST(wflag + x * 64 + j * 2 + wave, (unsigned)(t + 1));
      // deferred HBM output store (never read back)
      Y[((long)(x * 4 + bp) * TT + t) * 1024 + j * 32 + up] = hval;
    }
  }
}

// ---------------- launch ----------------
extern "C" void kernel_launch(void* const* d_in, const int* in_sizes, int n_in,
                              void* d_out, int out_size, void* d_ws, size_t ws_size,
                              hipStream_t stream) {
  const float* X = (const float*)d_in[0];
  const float* W = (const float*)d_in[1];
  const float* Rm = (const float*)d_in[2];
  const float* bias = (const float*)d_in[3];
  float* Y = (float*)d_out;
  char* ws = (char*)d_ws;

  const size_t off_flags = 0;           // 2048 B (512 wave-flags, dense)
  const size_t off_h = 4096;            // 131072 B (2 x 16384 x 4B f16-pairs)
  const size_t off_Zm = 135168;         // 1,048,576 B
  const size_t off_Wt = 1183744;        // 8,650,752 B (GPAD x 1024 f16)
  const size_t off_Rt = 9834496;        // 8,454,144 B (GG x 1024 f16)
  const size_t off_Zg = 18288640;       // 134,217,728 B
  const size_t need = off_Zg + (size_t)TT * 8 * 32 * 4 * 32 * 4 * 2;
  if (ws_size < need) return;  // fail visibly, never hang

  unsigned* wflag = (unsigned*)(ws + off_flags);
  unsigned* hbuf = (unsigned*)(ws + off_h);
  f16* Zm = (f16*)(ws + off_Zm);
  f16* Wt = (f16*)(ws + off_Wt);
  f16* Rt = (f16*)(ws + off_Rt);
  f16* Zg = (f16*)(ws + off_Zg);

  hipMemsetAsync(ws, 0, 135168, stream);  // flags + h parity buffers (h(0)=0)
  hipMemsetAsync(ws + off_Wt + (size_t)GG * 1024 * 2, 0, (size_t)(GPAD - GG) * 1024 * 2, stream);

  k_transpose_cvt<<<dim3(129, 32), 256, 0, stream>>>(W, Wt, 1024, GG);
  k_transpose_cvt<<<dim3(129, 32), 256, 0, stream>>>(Rm, Rt, 1024, GG);
  k_gemm_xw<<<dim3(128, 33), 256, 0, stream>>>(X, Wt, bias, Zm, Zg);

  k_onlstm<<<NBLK2, NTHR2, 20992, stream>>>(Zm, Zg, Rt, hbuf, wflag, Y);
}

// Round 12
// 3739.603 us; speedup vs baseline: 1.7352x; 1.7352x over previous
//
#include <hip/hip_runtime.h>

#define TT 512
#define GG 4128
#define GPAD 4224
#define NBLK2 64
#define NTHR2 512

typedef _Float16 f16;
typedef _Float16 half8 __attribute__((ext_vector_type(8)));
typedef _Float16 half4 __attribute__((ext_vector_type(4)));
typedef float f32x4 __attribute__((ext_vector_type(4)));
typedef unsigned u32x4 __attribute__((ext_vector_type(4)));
typedef unsigned long long ull;

__device__ __forceinline__ half8 h8(uint4 v) {
  union { uint4 u; half8 h; } c; c.u = v; return c.h;
}
__device__ __forceinline__ half8 h8v(u32x4 v) {
  union { u32x4 u; half8 h; } c; c.u = v; return c.h;
}

// coherent (L1/L2-bypassing) 16B load — device-scope visible
__device__ __forceinline__ u32x4 ld_cohx4(const unsigned* p) {
  u32x4 r;
  asm volatile("global_load_dwordx4 %0, %1, off sc0 sc1"
               : "=v"(r) : "v"(p) : "memory");
  return r;
}

// ---------------- transpose + f32->f16 convert: in[R][C] f32 -> out[C][R] f16 ----
__global__ void k_transpose_cvt(const float* __restrict__ in, f16* __restrict__ out,
                                int R, int C) {
  __shared__ float tile[32][33];
  int bx = blockIdx.x * 32, by = blockIdx.y * 32;
  int tx = threadIdx.x & 31, ty = threadIdx.x >> 5;
#pragma unroll
  for (int j = 0; j < 4; ++j) {
    int r = by + ty + j * 8;
    tile[ty + j * 8][tx] = in[(long)r * C + bx + tx];
  }
  __syncthreads();
#pragma unroll
  for (int j = 0; j < 4; ++j) {
    int c = bx + ty + j * 8;
    out[(long)c * R + by + tx] = (f16)tile[tx][ty + j * 8];
  }
}

// ---------------- phase 1: Z = X@W + bias, scattered into Zm / Zg layouts -------
// Zm: [t][b][32] f16   (master cols 0..31)
// Zg: [t][g 64][b 32][u 16][q 4] f16  (gate col n = 32 + q*1024 + g*16 + u)
__global__ __launch_bounds__(256) void k_gemm_xw(
    const float* __restrict__ X,
    const f16* __restrict__ Bt,
    const float* __restrict__ bias,
    f16* __restrict__ Zm,
    f16* __restrict__ Zg) {
  __shared__ f16 As[128 * 32];
  __shared__ f16 Bs[128 * 32];
  const int m0 = blockIdx.x * 128;
  const int n0 = blockIdx.y * 128;
  const int tid = threadIdx.x;
  const int wave = tid >> 6, lane = tid & 63;
  const int mrow = (wave & 1) * 64, ncol = (wave >> 1) * 64;
  f32x4 acc[4][4];
#pragma unroll
  for (int i = 0; i < 4; ++i)
#pragma unroll
    for (int j = 0; j < 4; ++j)
      acc[i][j] = (f32x4){0.f, 0.f, 0.f, 0.f};

  float4 ra[4];
  uint4 rb[2];
  auto load_tiles = [&](int k0) {
#pragma unroll
    for (int q = 0; q < 4; ++q) {
      int flat = q * 256 + tid;
      int r = flat >> 3, s = flat & 7;
      ra[q] = *(const float4*)(X + (long)(m0 + r) * 1024 + k0 + s * 4);
    }
#pragma unroll
    for (int q = 0; q < 2; ++q) {
      int flat = q * 256 + tid;
      int r = flat >> 2, s = flat & 3;
      rb[q] = *(const uint4*)(Bt + (long)(n0 + r) * 1024 + k0 + s * 8);
    }
  };
  load_tiles(0);
  for (int kt = 0; kt < 32; ++kt) {
    __syncthreads();
#pragma unroll
    for (int q = 0; q < 4; ++q) {
      int flat = q * 256 + tid;
      half4 h;
      h[0] = (f16)ra[q].x; h[1] = (f16)ra[q].y;
      h[2] = (f16)ra[q].z; h[3] = (f16)ra[q].w;
      *(half4*)((char*)As + flat * 8) = h;
    }
#pragma unroll
    for (int q = 0; q < 2; ++q) {
      int flat = q * 256 + tid;
      *(uint4*)((char*)Bs + flat * 16) = rb[q];
    }
    __syncthreads();
    if (kt + 1 < 32) load_tiles((kt + 1) * 32);
    const int kseg2 = ((lane >> 4) * 8) * 2;
    half8 af[4], bf[4];
#pragma unroll
    for (int i = 0; i < 4; ++i) {
      int r = mrow + i * 16 + (lane & 15);
      af[i] = *(const half8*)((const char*)As + r * 64 + kseg2);
      int c = ncol + i * 16 + (lane & 15);
      bf[i] = *(const half8*)((const char*)Bs + c * 64 + kseg2);
    }
#pragma unroll
    for (int i = 0; i < 4; ++i)
#pragma unroll
      for (int j = 0; j < 4; ++j)
        acc[i][j] = __builtin_amdgcn_mfma_f32_16x16x32_f16(af[i], bf[j], acc[i][j], 0, 0, 0);
  }
  // scatter epilogue
#pragma unroll
  for (int j = 0; j < 4; ++j) {
    int n = n0 + ncol + j * 16 + (lane & 15);
    if (n < GG) {
      float bv = bias[n];
      const int isM = (n < 32);
      int q = 0, u4 = 0, g2 = 0;
      if (!isM) {
        int k = n - 32;
        q = k >> 10;
        int u = k & 1023;
        g2 = u >> 4;
        u4 = u & 15;
      }
#pragma unroll
      for (int i = 0; i < 4; ++i) {
#pragma unroll
        for (int r = 0; r < 4; ++r) {
          int m = m0 + mrow + i * 16 + (lane >> 4) * 4 + r;
          int b = m >> 9, tt2 = m & 511;
          f16 v = (f16)(acc[i][j][r] + bv);
          if (isM)
            Zm[((long)(tt2 * 32 + b)) * 32 + n] = v;
          else
            Zg[((((long)tt2 * 64 + g2) * 32 + b) * 16 + u4) * 4 + q] = v;
        }
      }
    }
  }
}

// ---------------- phase 2 helpers ----------------
__device__ __forceinline__ float sigm(float x) { return 1.f / (1.f + __expf(-x)); }
__device__ __forceinline__ float tanh_(float x) {
  float ax = fabsf(x);
  float e = __expf(-2.f * ax);
  float t = (1.f - e) / (1.f + e);
  return copysignf(t, x);
}
#define AG_LD(p) __hip_atomic_load((p), __ATOMIC_RELAXED, __HIP_MEMORY_SCOPE_AGENT)
#define AG_ST(p, v) __hip_atomic_store((p), (v), __ATOMIC_RELAXED, __HIP_MEMORY_SCOPE_AGENT)

// barrier draining LDS ops only (vmem stays in flight)
__device__ __forceinline__ void bar_lds() {
  asm volatile("s_waitcnt lgkmcnt(0)" ::: "memory");
  __builtin_amdgcn_sched_barrier(0);
  __builtin_amdgcn_s_barrier();
  __builtin_amdgcn_sched_barrier(0);
}

// ---------------- phase 2: persistent recurrent kernel (R9, best-known) ----
// 64 blocks x 512 threads (8 waves). Block g owns units [g*16,+16) AND
// redundantly computes the 32 master columns; both ksplit-8 (wave = kq).
// SYNC (monotonic): producers publish h pairs -> vmcnt(0) -> s_barrier ->
// block flag = t+1. Consumers poll the 64 flags lane-parallel (>=), then
// coherent-load their own MFMA A-fragments straight to registers.
// Two LDS barriers/step (bar1 partials, bar2 zr) + 1 publish barrier.
// Masters cumsoftmax fully distributed per-thread.
// LDS: [0,64K) zp[kq8][q4][u16][b32] f32 | [64K,96K) zpm[kq8][col32][b32]
//      | [96K,100K) zr[col32][b32] f32.
__global__ __launch_bounds__(NTHR2, 2) void k_onlstm(
    const f16* __restrict__ Zm, const f16* __restrict__ Zg,
    const f16* __restrict__ Rt, unsigned* __restrict__ hbuf,
    unsigned* __restrict__ flagbuf, float* __restrict__ Y) {
  extern __shared__ char lds[];
  const int g = blockIdx.x, tid = threadIdx.x;
  const int wave = tid >> 6, lane = tid & 63;
  const int lr = lane & 15, lq = lane >> 4;
  const int kq = wave;                 // k-slice 0..7 (K=128)
  const int b = tid >> 4;              // batch (combine role)
  const int u = tid & 15;              // unit-in-block
  const int L0 = g >> 2;               // level of this block's units
  const int rb_ = tid & 31, rc = tid >> 5;  // masters-reduce role

  // pinned B fragments: gates 16 uint4, masters 8 uint4 (k-slice kq)
  uint4 bq[16], bm[8];
  {
    const f16* baseg = Rt + (long)kq * 128 + lq * 8;
#pragma unroll
    for (int q = 0; q < 4; ++q)
#pragma unroll
      for (int ks = 0; ks < 4; ++ks)
        bq[q * 4 + ks] = *(const uint4*)(baseg + (long)(32 + q * 1024 + g * 16 + lr) * 1024 + ks * 32);
#pragma unroll
    for (int ct = 0; ct < 2; ++ct)
#pragma unroll
      for (int ks = 0; ks < 4; ++ks)
        bm[ct * 4 + ks] = *(const uint4*)(baseg + (long)(ct * 16 + lr) * 1024 + ks * 32);
#pragma unroll
    for (int i = 0; i < 16; ++i)
      asm volatile("" : "+v"(bq[i].x), "+v"(bq[i].y), "+v"(bq[i].z), "+v"(bq[i].w));
#pragma unroll
    for (int i = 0; i < 8; ++i)
      asm volatile("" : "+v"(bm[i].x), "+v"(bm[i].y), "+v"(bm[i].z), "+v"(bm[i].w));
  }
  float creg = 0.f;
  // word bases into h buffer for this lane's A-fragment rows (batch lr, lr+16)
  const int wb0 = lr * 512 + kq * 64 + lq * 4;
  const int wb1 = (lr + 16) * 512 + kq * 64 + lq * 4;

  for (int t = 0; t < TT; ++t) {
    // --- prefetches of precomputed inputs (plain cached, immutable) ---
    half4 zxh = *(const half4*)(Zg + ((((long)t * 64 + g) * 32 + b) * 16 + u) * 4);
    f16 zm0 = Zm[((long)t * 32 + rb_) * 32 + rc];
    f16 zm1 = Zm[((long)t * 32 + rb_) * 32 + rc + 16];
    // --- monotonic flag poll: all 64 block flags >= t (lane-parallel) ---
    if (t > 0) {
      const unsigned tg = (unsigned)t;
      for (;;) {
        unsigned v = AG_LD(flagbuf + lane * 16);
        if (__all((int)(v >= tg))) break;
      }
    }
    // --- load own A-fragments directly to registers (coherent, one RT) ---
    const unsigned* hb = hbuf + (t & 1) * 16384;
    u32x4 ha[8];
#pragma unroll
    for (int ks = 0; ks < 4; ++ks) {
      ha[ks] = ld_cohx4(hb + wb0 + ks * 16);
      ha[4 + ks] = ld_cohx4(hb + wb1 + ks * 16);
    }
    asm volatile("s_waitcnt vmcnt(0)" ::: "memory");
    __builtin_amdgcn_sched_barrier(0);
    // --- MFMA from registers: gates 4q x 2bt, masters 2ct x 2bt ---
    f32x4 acc[4][2], accm[2][2];
#pragma unroll
    for (int q = 0; q < 4; ++q) {
      acc[q][0] = (f32x4){0.f, 0.f, 0.f, 0.f};
      acc[q][1] = (f32x4){0.f, 0.f, 0.f, 0.f};
    }
#pragma unroll
    for (int ct = 0; ct < 2; ++ct) {
      accm[ct][0] = (f32x4){0.f, 0.f, 0.f, 0.f};
      accm[ct][1] = (f32x4){0.f, 0.f, 0.f, 0.f};
    }
#pragma unroll
    for (int ks = 0; ks < 4; ++ks) {
      half8 a0 = h8v(ha[ks]);
      half8 a1 = h8v(ha[4 + ks]);
#pragma unroll
      for (int q = 0; q < 4; ++q) {
        acc[q][0] = __builtin_amdgcn_mfma_f32_16x16x32_f16(a0, h8(bq[q * 4 + ks]), acc[q][0], 0, 0, 0);
        acc[q][1] = __builtin_amdgcn_mfma_f32_16x16x32_f16(a1, h8(bq[q * 4 + ks]), acc[q][1], 0, 0, 0);
      }
#pragma unroll
      for (int ct = 0; ct < 2; ++ct) {
        accm[ct][0] = __builtin_amdgcn_mfma_f32_16x16x32_f16(a0, h8(bm[ct * 4 + ks]), accm[ct][0], 0, 0, 0);
        accm[ct][1] = __builtin_amdgcn_mfma_f32_16x16x32_f16(a1, h8(bm[ct * 4 + ks]), accm[ct][1], 0, 0, 0);
      }
    }
    // --- write partials: zp (gates) + zpm (masters) ---
#pragma unroll
    for (int q = 0; q < 4; ++q)
#pragma unroll
      for (int bt = 0; bt < 2; ++bt) {
        int bsw = (bt * 16 + lq * 4) ^ ((lr & 7) << 2);
        *(f32x4*)(lds + (((kq * 64 + q * 16 + lr) * 32 + bsw) << 2)) = acc[q][bt];
      }
#pragma unroll
    for (int ct = 0; ct < 2; ++ct)
#pragma unroll
      for (int bt = 0; bt < 2; ++bt) {
        int colm = ct * 16 + lr;
        int bsw = (bt * 16 + lq * 4) ^ ((colm & 7) << 2);
        *(f32x4*)(lds + 65536 + (((kq * 32 + colm) * 32 + bsw) << 2)) = accm[ct][bt];
      }
    bar_lds();  // bar1: zp + zpm visible
    // --- gate reduce (own z) + masters reduce (zr) ---
    float z[4];
    {
      int bswg = b ^ ((u & 7) << 2);
#pragma unroll
      for (int q = 0; q < 4; ++q) {
        float s = 0.f;
#pragma unroll
        for (int k8 = 0; k8 < 8; ++k8)
          s += *(const float*)(lds + (((k8 * 64 + q * 16 + u) * 32 + bswg) << 2));
        z[q] = s + (float)zxh[q];
      }
    }
#pragma unroll
    for (int rep = 0; rep < 2; ++rep) {
      int c = rc + rep * 16;
      int bswm = rb_ ^ ((c & 7) << 2);
      float s = 0.f;
#pragma unroll
      for (int k8 = 0; k8 < 8; ++k8)
        s += *(const float*)(lds + 65536 + (((k8 * 32 + c) * 32 + bswm) << 2));
      s += (float)(rep ? zm1 : zm0);
      *(float*)(lds + 98304 + ((c * 32 + bswm) << 2)) = s;
    }
    bar_lds();  // bar2: zr visible
    // --- per-thread cumsoftmax at (b, L0) + gates + combine ---
    float vf[16], vi[16];
#pragma unroll
    for (int j = 0; j < 16; ++j) {
      int bsw = b ^ ((j & 7) << 2);
      vf[j] = *(const float*)(lds + 98304 + (((j * 32) + bsw) << 2));
      vi[j] = *(const float*)(lds + 98304 + ((((16 + j) * 32) + bsw) << 2));
    }
    float mf = vf[0], mi = vi[0];
#pragma unroll
    for (int j = 1; j < 16; ++j) { mf = fmaxf(mf, vf[j]); mi = fmaxf(mi, vi[j]); }
    float sf = 0.f, pf = 0.f, si = 0.f, pi = 0.f;
#pragma unroll
    for (int j = 0; j < 16; ++j) {
      float ef = __expf(vf[j] - mf);
      sf += ef;
      if (j <= L0) pf += ef;
      float ei = __expf(vi[j] - mi);
      si += ei;
      if (j >= L0) pi += ei;
    }
    float fm = pf / sf, im = pi / si;
    float f = sigm(z[0]), i_ = sigm(z[1]), o = sigm(z[2]);
    float ci = tanh_(z[3]);
    float ov = fm * im;
    float cn = ov * (f * creg + i_ * ci) + (fm - ov) * creg + (im - ov) * ci;
    creg = cn;
    float hval = o * tanh_(cn);
    // --- publish h pair, drain, barrier, flag (R4-proven ordering) ---
    float hp = __shfl_xor(hval, 1);
    if (!(u & 1)) {
      union { f16 h[2]; unsigned w; } pk;
      pk.h[0] = (f16)hval;
      pk.h[1] = (f16)hp;
      AG_ST(hbuf + ((t + 1) & 1) * 16384 + b * 512 + g * 8 + (u >> 1), pk.w);
    }
    asm volatile("s_waitcnt vmcnt(0)" ::: "memory");
    __builtin_amdgcn_s_barrier();
    if (tid == 0) AG_ST(flagbuf + g * 16, (unsigned)(t + 1));
    // deferred HBM output store (never read back; drained next step)
    Y[((long)b * TT + t) * 1024 + g * 16 + u] = hval;
  }
}

// ---------------- launch ----------------
extern "C" void kernel_launch(void* const* d_in, const int* in_sizes, int n_in,
                              void* d_out, int out_size, void* d_ws, size_t ws_size,
                              hipStream_t stream) {
  const float* X = (const float*)d_in[0];
  const float* W = (const float*)d_in[1];
  const float* Rm = (const float*)d_in[2];
  const float* bias = (const float*)d_in[3];
  float* Y = (float*)d_out;
  char* ws = (char*)d_ws;

  const size_t off_flags = 0;           // 4096 B (64 flags x 64B stride)
  const size_t off_h = 4096;            // 131072 B (2 x 16384 x 4B f16-pairs)
  const size_t off_Zm = 135168;         // 1,048,576 B
  const size_t off_Wt = 1183744;        // 8,650,752 B (GPAD x 1024 f16)
  const size_t off_Rt = 9834496;        // 8,454,144 B (GG x 1024 f16)
  const size_t off_Zg = 18288640;       // 134,217,728 B
  const size_t need = off_Zg + (size_t)TT * 64 * 32 * 16 * 4 * 2;
  if (ws_size < need) return;  // fail visibly, never hang

  unsigned* flagbuf = (unsigned*)(ws + off_flags);
  unsigned* hbuf = (unsigned*)(ws + off_h);
  f16* Zm = (f16*)(ws + off_Zm);
  f16* Wt = (f16*)(ws + off_Wt);
  f16* Rt = (f16*)(ws + off_Rt);
  f16* Zg = (f16*)(ws + off_Zg);

  hipMemsetAsync(ws, 0, 135168, stream);  // flags + h parity buffers (h(0)=0)
  hipMemsetAsync(ws + off_Wt + (size_t)GG * 1024 * 2, 0, (size_t)(GPAD - GG) * 1024 * 2, stream);

  k_transpose_cvt<<<dim3(129, 32), 256, 0, stream>>>(W, Wt, 1024, GG);
  k_transpose_cvt<<<dim3(129, 32), 256, 0, stream>>>(Rm, Rt, 1024, GG);
  k_gemm_xw<<<dim3(128, 33), 256, 0, stream>>>(X, Wt, bias, Zm, Zg);

  hipFuncSetAttribute((const void*)k_onlstm, hipFuncAttributeMaxDynamicSharedMemorySize, 102400);
  k_onlstm<<<NBLK2, NTHR2, 102400, stream>>>(Zm, Zg, Rt, hbuf, flagbuf, Y);
}